// Round 8
// baseline (286.796 us; speedup 1.0000x reference)
//
#include <hip/hip_runtime.h>
#include <stdint.h>

#define BATCH 256
#define DBLK  16          // d
#define OB    128         // hidden nodes per diagonal block (M)
#define NN    2048        // M*D

using bf16x8  = __attribute__((ext_vector_type(8))) __bf16;
using f32x4   = __attribute__((ext_vector_type(4))) float;
using ushort8 = __attribute__((ext_vector_type(8))) unsigned short;

__device__ __forceinline__ unsigned short f2bf(float f) {
    union { float f; uint32_t u; } v; v.f = f;
    uint32_t u = v.u;
    uint32_t r = (u + 0x7fffu + ((u >> 16) & 1u)) >> 16;   // RNE
    return (unsigned short)r;
}

__device__ __forceinline__ float bf2f(unsigned short h) {
    union { uint32_t u; float f; } v; v.u = ((uint32_t)h) << 16;
    return v.f;
}

// fused fast tanh + log|tanh'|: one __expf + one __logf.
__device__ __forceinline__ void act_tanh_lga(float x, float& th, float& lga) {
    float ax = fabsf(x);
    float e  = __expf(-2.f * ax);
    float p  = 1.f + e;
    float t  = 1.f - __fdividef(2.f * e, p);
    th  = (x < 0.f) ? -t : t;
    lga = 2.f * (0.69314718055994531f - ax - __logf(p));
}

__device__ __forceinline__ ushort8 pack_bf8(float4 a, float4 b) {
    ushort8 u;
    u[0] = f2bf(a.x); u[1] = f2bf(a.y); u[2] = f2bf(a.z); u[3] = f2bf(a.w);
    u[4] = f2bf(b.x); u[5] = f2bf(b.y); u[6] = f2bf(b.z); u[7] = f2bf(b.w);
    return u;
}

// ---- layer0 for one batch row, threads t=0..255: thread t -> outputs j=t*8..t*8+7
__device__ __forceinline__ void l0_block(const float* __restrict__ xs,
                                         const float* __restrict__ W0,
                                         const float* __restrict__ b0,
                                         unsigned short* __restrict__ h0,
                                         unsigned short* __restrict__ e0,
                                         float* __restrict__ mmax,
                                         int b, int t) {
    const int j0 = t * 8;
    const int dd = t >> 4;
    float g[8];
    unsigned short hv[8];
    float lm = -1e30f;
    #pragma unroll
    for (int q = 0; q < 8; ++q) {
        const int j = j0 + q;
        const float* wrow = W0 + (size_t)j * DBLK;
        float s = b0[j];
        #pragma unroll
        for (int c = 0; c < DBLK; c += 4) {
            float4 wv = *(const float4*)(wrow + c);
            s += wv.x * xs[c] + wv.y * xs[c + 1] + wv.z * xs[c + 2] + wv.w * xs[c + 3];
        }
        float th, lga;
        act_tanh_lga(s, th, lga);
        hv[q] = f2bf(th);
        g[q]  = __logf(wrow[dd]) + lga;
        lm = fmaxf(lm, g[q]);
    }
    #pragma unroll
    for (int off = 1; off < 16; off <<= 1) lm = fmaxf(lm, __shfl_xor(lm, off));
    ushort8 hh, ee;
    #pragma unroll
    for (int q = 0; q < 8; ++q) {
        hh[q] = hv[q];
        ee[q] = f2bf(__expf(g[q] - lm));
    }
    *(ushort8*)(h0 + (size_t)b * NN + j0) = hh;
    *(ushort8*)(e0 + (size_t)b * NN + j0) = ee;
    if ((t & 15) == 0) mmax[b * DBLK + dd] = lm;
}

// ---- P1: blocks [0,1024): convert flow0 W1 pair {p, 2047-p} (loads hoisted);
//          blocks [1024,1280): layer0 of flow 0 + zero tickets
__global__ void k_prep(const float* __restrict__ W1a,
                       unsigned short* __restrict__ W1bf,
                       const float* __restrict__ inp,
                       const float* __restrict__ W00,
                       const float* __restrict__ b00,
                       unsigned short* __restrict__ h0,
                       unsigned short* __restrict__ e0,
                       float* __restrict__ mmax,
                       int* __restrict__ cnt) {
    const int gb = blockIdx.x;
    const int t  = threadIdx.x;
    if (gb < 1024) {
        const int p     = gb;
        const int kend0 = ((p >> 7) + 1) * OB;
        const float* s0 = W1a + (size_t)p * NN;
        const float* s1 = W1a + (size_t)(NN - 1 - p) * NN;
        unsigned short* d0 = W1bf + (size_t)p * NN;
        unsigned short* d1 = W1bf + (size_t)(NN - 1 - p) * NN;
        float4 va[2][2];
        unsigned short* dp[2];
        bool act[2];
        #pragma unroll
        for (int i = 0; i < 2; ++i) {
            const int c  = t + i * 256;
            act[i] = (c < 272);
            if (act[i]) {
                const int off = c * 8;
                const float* sp;
                if (off < kend0) { sp = s0 + off;           dp[i] = d0 + off; }
                else             { sp = s1 + (off - kend0); dp[i] = d1 + (off - kend0); }
                va[i][0] = *(const float4*)(sp);
                va[i][1] = *(const float4*)(sp + 4);
            }
        }
        #pragma unroll
        for (int i = 0; i < 2; ++i)
            if (act[i]) *(ushort8*)dp[i] = pack_bf8(va[i][0], va[i][1]);
    } else {
        const int b = gb - 1024;
        if (b == 0 && t < 32) cnt[t] = 0;
        l0_block(inp + (size_t)b * DBLK, W00, b00, h0, e0, mmax, b, t);
    }
}

// ---- mega kernel: layer1 GEMM tiles + fence-free ticketed per-bt finisher.
// grid (dd=16, bt=16, z): z<4 = layer1 ct; FLOW==0 && z==4 = convert flow1 W1.
// Cross-block handoff (h1 pairs, g1) uses RELAXED AGENT-scope atomics (sc1,
// coherent through Infinity Cache) — NO threadfence (R6's wbl2 disaster).
template<int FLOW>
__global__ void __launch_bounds__(512, 4)
k_flow(const unsigned short* __restrict__ h0,
       const unsigned short* __restrict__ W1b,
       const float* __restrict__ b1v,
       const unsigned short* __restrict__ e0,
       const float* __restrict__ mmax,
       unsigned int* __restrict__ h1p,          // packed 2xbf16 per u32
       float* __restrict__ g1,
       const float* __restrict__ W2,
       int* __restrict__ cnt,
       const float* __restrict__ W1next,        // FLOW==0: flow1 W1 fp32
       unsigned short* __restrict__ W1bfn,      // FLOW==0: flow1 W1 bf16 out
       const float* __restrict__ W0n,           // FLOW==0: flow1 layer0
       const float* __restrict__ b0n,
       unsigned short* __restrict__ h0n,
       unsigned short* __restrict__ e0n,
       float* __restrict__ mmaxn,
       float* __restrict__ ld0,
       float* __restrict__ out_final,
       float* __restrict__ ld_final) {
    const int tid = threadIdx.x;

    if (FLOW == 0 && blockIdx.z == 4) {
        const int cid = (int)blockIdx.x * 16 + (int)blockIdx.y;   // 0..255
        float4 va[3][2];
        unsigned short* dp[3];
        bool act[3];
        #pragma unroll
        for (int i = 0; i < 3; ++i) {
            const int c = tid + i * 512;
            act[i] = (c < 1088);
            if (act[i]) {
                const int pi  = c / 272;
                const int rem = c - pi * 272;
                const int p   = cid * 4 + pi;
                const int kend0 = ((p >> 7) + 1) * OB;
                const int off = rem * 8;
                const int row = (off < kend0) ? p : (NN - 1 - p);
                const int k   = (off < kend0) ? off : (off - kend0);
                const float* sp = W1next + (size_t)row * NN + k;
                dp[i] = W1bfn + (size_t)row * NN + k;
                va[i][0] = *(const float4*)(sp);
                va[i][1] = *(const float4*)(sp + 4);
            }
        }
        #pragma unroll
        for (int i = 0; i < 3; ++i)
            if (act[i]) *(ushort8*)dp[i] = pack_bf8(va[i][0], va[i][1]);
        return;
    }

    const int dd    = blockIdx.x;
    const int bt    = blockIdx.y;
    const int ct    = blockIdx.z;
    const int w     = tid >> 6;      // 0..7
    const int lane  = tid & 63;
    const int brow0 = bt * 16;
    const int arow  = brow0 + (lane & 15);
    const int koff  = (lane >> 4) * 8;
    const int ncol  = lane & 15;
    const int col0  = dd * OB + ct * 32;

    f32x4 acc[2], acc2[2];
    #pragma unroll
    for (int nt = 0; nt < 2; ++nt) {
        acc[nt]  = (f32x4){0.f, 0.f, 0.f, 0.f};
        acc2[nt] = (f32x4){0.f, 0.f, 0.f, 0.f};
    }

    const unsigned short* Ab = h0 + (size_t)arow * NN + koff;
    const unsigned short* Bb[2];
    #pragma unroll
    for (int nt = 0; nt < 2; ++nt)
        Bb[nt] = W1b + (size_t)(col0 + nt * 16 + ncol) * NN + koff;

    const int nch = (dd + 1) * 4;
    #pragma unroll 4
    for (int c = w; c < nch; c += 8) {
        const int k = c * 32;
        bf16x8 a   = *(const bf16x8*)(Ab + k);
        bf16x8 b0v = *(const bf16x8*)(Bb[0] + k);
        bf16x8 b1w = *(const bf16x8*)(Bb[1] + k);
        acc[0] = __builtin_amdgcn_mfma_f32_16x16x32_bf16(a, b0v, acc[0], 0, 0, 0);
        acc[1] = __builtin_amdgcn_mfma_f32_16x16x32_bf16(a, b1w, acc[1], 0, 0, 0);
    }

    if (w < 4) {
        const int k2 = dd * OB + w * 32;
        bf16x8 a = *(const bf16x8*)(e0 + (size_t)arow * NN + koff + k2);
        acc2[0] = __builtin_amdgcn_mfma_f32_16x16x32_bf16(a, *(const bf16x8*)(Bb[0] + k2), acc2[0], 0, 0, 0);
        acc2[1] = __builtin_amdgcn_mfma_f32_16x16x32_bf16(a, *(const bf16x8*)(Bb[1] + k2), acc2[1], 0, 0, 0);
    }

    __shared__ float ls1[8][2][64][4];
    __shared__ float ls2[4][2][64][4];
    #pragma unroll
    for (int nt = 0; nt < 2; ++nt)
        *(f32x4*)&ls1[w][nt][lane][0] = acc[nt];
    if (w < 4) {
        #pragma unroll
        for (int nt = 0; nt < 2; ++nt)
            *(f32x4*)&ls2[w][nt][lane][0] = acc2[nt];
    }
    __syncthreads();

    {
        const int o  = tid;                    // 0..511 output index in tile
        const int rr = o >> 5;                 // 0..15 row in tile
        const int cc = o & 31;                 // 0..31 col in tile
        const int nt = cc >> 4;
        const int r  = rr & 3;
        const int ls = (rr >> 2) * 16 + (cc & 15);
        float S = 0.f, S2 = 0.f;
        #pragma unroll
        for (int ww = 0; ww < 8; ++ww) S += ls1[ww][nt][ls][r];
        #pragma unroll
        for (int ww = 0; ww < 4; ++ww) S2 += ls2[ww][nt][ls][r];
        const int j    = col0 + cc;
        const int brow = brow0 + rr;
        const float pre = S + b1v[j];
        float th, lga;
        act_tanh_lga(pre, th, lga);
        float gv = __logf(S2) + mmax[brow * DBLK + dd] + lga;
        __hip_atomic_store(&g1[(size_t)brow * NN + j], gv,
                           __ATOMIC_RELAXED, __HIP_MEMORY_SCOPE_AGENT);
        unsigned int hbf = f2bf(th);
        unsigned int other = __shfl_xor(hbf, 1);
        if ((cc & 1) == 0) {
            unsigned int packed = hbf | (other << 16);
            __hip_atomic_store(&h1p[((size_t)brow * NN + j) >> 1], packed,
                               __ATOMIC_RELAXED, __HIP_MEMORY_SCOPE_AGENT);
        }
    }

    // ---- ticket: __syncthreads drains vmcnt (sc1 stores globally visible),
    //      then a RELAXED agent add. 64th block runs the finisher. No fences.
    __shared__ int is_last;
    __syncthreads();
    if (tid == 0) {
        int old = __hip_atomic_fetch_add(&cnt[bt], 1, __ATOMIC_RELAXED,
                                         __HIP_MEMORY_SCOPE_AGENT);
        is_last = (old == 63);
    }
    __syncthreads();
    if (!is_last) return;

    // ---- finisher: final linear layer + lse for this tile's 16 rows ----
    __shared__ float sxs[16][16];    // [rr][dd2] x-row after final layer
    __shared__ float gfs[16][16];    // [rr][dd2] final lse
    const int slot = lane >> 4;
    const int sl   = lane & 15;
    #pragma unroll
    for (int round = 0; round < 8; ++round) {
        const int p   = round * 32 + w * 4 + slot;   // 0..255 = (rr2, dd2)
        const int rr2 = p >> 4;
        const int dd2 = p & 15;
        const int r2  = brow0 + rr2;
        const unsigned int* hrow = h1p + (size_t)r2 * (NN / 2);
        const float* w2r = W2 + (size_t)dd2 * NN;
        const int kend = (dd2 + 1) * OB;
        float s = 0.f;
        for (int k = sl * 4; k < kend; k += 64) {
            unsigned int p0 = __hip_atomic_load(&hrow[(k >> 1) + 0],
                                                __ATOMIC_RELAXED, __HIP_MEMORY_SCOPE_AGENT);
            unsigned int p1 = __hip_atomic_load(&hrow[(k >> 1) + 1],
                                                __ATOMIC_RELAXED, __HIP_MEMORY_SCOPE_AGENT);
            float4 wv = *(const float4*)(w2r + k);
            s += bf2f((unsigned short)(p0 & 0xffffu)) * wv.x
               + bf2f((unsigned short)(p0 >> 16))     * wv.y
               + bf2f((unsigned short)(p1 & 0xffffu)) * wv.z
               + bf2f((unsigned short)(p1 >> 16))     * wv.w;
        }
        #pragma unroll
        for (int off = 8; off > 0; off >>= 1) s += __shfl_xor(s, off);
        const float* grow = g1 + (size_t)r2 * NN + dd2 * OB;
        float v[8];
        #pragma unroll
        for (int j2 = 0; j2 < 8; ++j2)
            v[j2] = __hip_atomic_load(&grow[sl + j2 * 16],
                                      __ATOMIC_RELAXED, __HIP_MEMORY_SCOPE_AGENT);
        float mx = v[0];
        #pragma unroll
        for (int j2 = 1; j2 < 8; ++j2) mx = fmaxf(mx, v[j2]);
        #pragma unroll
        for (int off = 8; off > 0; off >>= 1) mx = fmaxf(mx, __shfl_xor(mx, off));
        float e = 0.f;
        #pragma unroll
        for (int j2 = 0; j2 < 8; ++j2)
            e += __expf(v[j2] - mx) * w2r[dd2 * OB + sl + j2 * 16];
        #pragma unroll
        for (int off = 8; off > 0; off >>= 1) e += __shfl_xor(e, off);
        if (sl == 0) {
            sxs[rr2][dd2] = s;
            gfs[rr2][dd2] = __logf(e) + mx;
        }
    }
    __syncthreads();

    if (tid < 16) {
        float ldv = 0.f;
        #pragma unroll
        for (int q = 0; q < DBLK; ++q) ldv += gfs[tid][q];
        if (FLOW == 0) ld0[brow0 + tid] = ldv;
        else           ld_final[brow0 + tid] = ldv + ld0[brow0 + tid];
    }
    if (FLOW == 0) {
        #pragma unroll
        for (int half = 0; half < 8; ++half) {
            const int rr2 = half * 2 + (tid >> 8);
            l0_block(&sxs[rr2][0], W0n, b0n, h0n, e0n, mmaxn, brow0 + rr2, tid & 255);
        }
    } else {
        if (tid < 256)
            out_final[(size_t)(brow0 + (tid >> 4)) * DBLK + (tid & 15)] = sxs[tid >> 4][tid & 15];
    }
}

extern "C" void kernel_launch(void* const* d_in, const int* in_sizes, int n_in,
                              void* d_out, int out_size, void* d_ws, size_t ws_size,
                              hipStream_t stream) {
    const float* inp   = (const float*)d_in[0];
    const float* W0[2] = {(const float*)d_in[1], (const float*)d_in[6]};
    const float* W1[2] = {(const float*)d_in[2], (const float*)d_in[7]};
    const float* W2[2] = {(const float*)d_in[3], (const float*)d_in[8]};
    const float* b0[2] = {(const float*)d_in[4], (const float*)d_in[9]};
    const float* b1[2] = {(const float*)d_in[5], (const float*)d_in[10]};

    char* w = (char*)d_ws;
    size_t off = 0;
    unsigned short* W1bf = (unsigned short*)(w + off); off += (size_t)2 * NN * NN * 2; // 16 MB
    unsigned short* h0a  = (unsigned short*)(w + off); off += (size_t)BATCH * NN * 2;
    unsigned short* e0a  = (unsigned short*)(w + off); off += (size_t)BATCH * NN * 2;
    unsigned short* h0c  = (unsigned short*)(w + off); off += (size_t)BATCH * NN * 2;
    unsigned short* e0c  = (unsigned short*)(w + off); off += (size_t)BATCH * NN * 2;
    float* mmax0 = (float*)(w + off); off += (size_t)BATCH * DBLK * 4;
    float* mmax1 = (float*)(w + off); off += (size_t)BATCH * DBLK * 4;
    unsigned int* h1p = (unsigned int*)(w + off); off += (size_t)BATCH * (NN / 2) * 4; // 1 MB
    float* g1   = (float*)(w + off); off += (size_t)BATCH * NN * 4;                    // 2 MB
    float* ld0  = (float*)(w + off); off += (size_t)BATCH * 4;
    int*   cnt  = (int*)(w + off);   off += 32 * 4;

    float* out_final = (float*)d_out;                 // (256,16)
    float* ld_final  = (float*)d_out + BATCH * DBLK;  // (256,)

    // P1: convert flow0 W1 + layer0 flow 0 + zero tickets
    k_prep<<<dim3(1024 + BATCH), dim3(256), 0, stream>>>(
        W1[0], W1bf, inp, W0[0], b0[0], h0a, e0a, mmax0, cnt);

    // P2: flow 0 — layer1 GEMM + ticketed finisher (final0 + layer0 of flow1),
    //     overlapped with flow1 W1 conversion (z==4)
    k_flow<0><<<dim3(DBLK, 16, 5), dim3(512), 0, stream>>>(
        h0a, W1bf, b1[0], e0a, mmax0, h1p, g1, W2[0], cnt,
        W1[1], W1bf + (size_t)NN * NN,
        W0[1], b0[1], h0c, e0c, mmax1,
        ld0, nullptr, nullptr);

    // P3: flow 1 — layer1 GEMM + ticketed finisher (final1 -> d_out)
    k_flow<1><<<dim3(DBLK, 16, 4), dim3(512), 0, stream>>>(
        h0c, W1bf + (size_t)NN * NN, b1[1], e0c, mmax1, h1p, g1, W2[1], cnt + 16,
        nullptr, nullptr, nullptr, nullptr, nullptr, nullptr, nullptr,
        ld0, out_final, ld_final);
}

// Round 10
// 197.692 us; speedup vs baseline: 1.4507x; 1.4507x over previous
//
#include <hip/hip_runtime.h>
#include <hip/hip_cooperative_groups.h>
#include <stdint.h>

namespace cg = cooperative_groups;

#define BATCH 256
#define DBLK  16          // d
#define OB    128         // hidden nodes per diagonal block (M)
#define NN    2048        // M*D
#define NB    256         // cooperative blocks (1/CU — co-residency guaranteed)
#define NT    1024        // threads per block (16 waves)

#define CHUNKS_PER_FLOW (1024 * 272)          // 278528 (8-float chunks, row-pair packed)
#define CHUNKS_TOTAL    (2 * CHUNKS_PER_FLOW) // 557056

using bf16x8  = __attribute__((ext_vector_type(8))) __bf16;
using f32x4   = __attribute__((ext_vector_type(4))) float;
using ushort8 = __attribute__((ext_vector_type(8))) unsigned short;

__device__ __forceinline__ unsigned short f2bf(float f) {
    union { float f; uint32_t u; } v; v.f = f;
    uint32_t u = v.u;
    uint32_t r = (u + 0x7fffu + ((u >> 16) & 1u)) >> 16;   // RNE
    return (unsigned short)r;
}

__device__ __forceinline__ float bf2f(unsigned short h) {
    union { uint32_t u; float f; } v; v.u = ((uint32_t)h) << 16;
    return v.f;
}

// fused fast tanh + log|tanh'|: one __expf + one __logf.
__device__ __forceinline__ void act_tanh_lga(float x, float& th, float& lga) {
    float ax = fabsf(x);
    float e  = __expf(-2.f * ax);
    float p  = 1.f + e;
    float t  = 1.f - __fdividef(2.f * e, p);
    th  = (x < 0.f) ? -t : t;
    lga = 2.f * (0.69314718055994531f - ax - __logf(p));
}

__device__ __forceinline__ ushort8 pack_bf8(float4 a, float4 b) {
    ushort8 u;
    u[0] = f2bf(a.x); u[1] = f2bf(a.y); u[2] = f2bf(a.z); u[3] = f2bf(a.w);
    u[4] = f2bf(b.x); u[5] = f2bf(b.y); u[6] = f2bf(b.z); u[7] = f2bf(b.w);
    return u;
}

// ---- W1 fp32 -> bf16 conversion over both flows, hoisted-load pipelined.
// Virtual chunk space: flow f, row-pair p={p,2047-p}, 272 chunks of 8 floats.
template<int N>
__device__ __forceinline__ void conv_phase(int gtid, int stride,
                                           const float* __restrict__ W1a,
                                           const float* __restrict__ W1c,
                                           unsigned short* __restrict__ W1bf) {
    float4 va[N][2];
    unsigned short* dp[N];
    bool act[N];
    #pragma unroll
    for (int i = 0; i < N; ++i) {
        const int c = gtid + i * stride;
        act[i] = (c < CHUNKS_TOTAL);
        if (act[i]) {
            const int f   = (c >= CHUNKS_PER_FLOW);
            const int r   = c - f * CHUNKS_PER_FLOW;
            const int p   = r / 272;
            const int rem = r - p * 272;
            const int kend0 = ((p >> 7) + 1) * OB;
            const int off = rem * 8;
            const int row = (off < kend0) ? p : (NN - 1 - p);
            const int k   = (off < kend0) ? off : (off - kend0);
            const float* sp = (f ? W1c : W1a) + (size_t)row * NN + k;
            dp[i] = W1bf + (size_t)f * NN * NN + (size_t)row * NN + k;
            va[i][0] = *(const float4*)(sp);
            va[i][1] = *(const float4*)(sp + 4);
        }
    }
    #pragma unroll
    for (int i = 0; i < N; ++i)
        if (act[i]) *(ushort8*)dp[i] = pack_bf8(va[i][0], va[i][1]);
}

// ---- layer0 for one batch row, 1024 threads: wave w == dd, lane -> 2 outputs.
__device__ __forceinline__ void l0_wave(const float* __restrict__ xs,   // 16 floats
                                        const float* __restrict__ W0,
                                        const float* __restrict__ b0,
                                        unsigned short* __restrict__ h0,
                                        unsigned short* __restrict__ e0,
                                        float* __restrict__ mmax,
                                        int b, int tid) {
    const int dd   = tid >> 6;
    const int lane = tid & 63;
    const int j0   = dd * OB + lane * 2;
    float g[2];
    unsigned short hv[2];
    float lm = -1e30f;
    #pragma unroll
    for (int q = 0; q < 2; ++q) {
        const int j = j0 + q;
        const float* wrow = W0 + (size_t)j * DBLK;
        float s = b0[j];
        #pragma unroll
        for (int c = 0; c < DBLK; c += 4) {
            float4 wv = *(const float4*)(wrow + c);
            s += wv.x * xs[c] + wv.y * xs[c + 1] + wv.z * xs[c + 2] + wv.w * xs[c + 3];
        }
        float th, lga;
        act_tanh_lga(s, th, lga);
        hv[q] = f2bf(th);
        g[q]  = __logf(wrow[dd]) + lga;
        lm = fmaxf(lm, g[q]);
    }
    #pragma unroll
    for (int off = 32; off > 0; off >>= 1) lm = fmaxf(lm, __shfl_xor(lm, off));
    ushort2 hh, ee;
    hh.x = hv[0]; hh.y = hv[1];
    ee.x = f2bf(__expf(g[0] - lm));
    ee.y = f2bf(__expf(g[1] - lm));
    *(ushort2*)(h0 + (size_t)b * NN + j0) = hh;
    *(ushort2*)(e0 + (size_t)b * NN + j0) = ee;
    if (lane == 0) mmax[b * DBLK + dd] = lm;
}

// ---- one layer1 output tile (16 rows x 32 cols), 16 waves, K split 16 ways ----
__device__ __forceinline__ void l1_tile(int dd, int bt, int ct, int tid,
                                        const unsigned short* __restrict__ h0,
                                        const unsigned short* __restrict__ W1b,
                                        const float* __restrict__ b1v,
                                        const unsigned short* __restrict__ e0,
                                        const float* __restrict__ mmax,
                                        unsigned short* __restrict__ h1,
                                        float* __restrict__ g1,
                                        float (*ls1)[2][64][4],
                                        float (*ls2)[2][64][4]) {
    const int w     = tid >> 6;      // 0..15
    const int lane  = tid & 63;
    const int brow0 = bt * 16;
    const int arow  = brow0 + (lane & 15);
    const int koff  = (lane >> 4) * 8;
    const int ncol  = lane & 15;
    const int col0  = dd * OB + ct * 32;

    __syncthreads();                 // LDS from previous tile fully consumed

    f32x4 acc[2], acc2[2];
    #pragma unroll
    for (int nt = 0; nt < 2; ++nt) {
        acc[nt]  = (f32x4){0.f, 0.f, 0.f, 0.f};
        acc2[nt] = (f32x4){0.f, 0.f, 0.f, 0.f};
    }

    const unsigned short* Ab = h0 + (size_t)arow * NN + koff;
    const unsigned short* Bb[2];
    #pragma unroll
    for (int nt = 0; nt < 2; ++nt)
        Bb[nt] = W1b + (size_t)(col0 + nt * 16 + ncol) * NN + koff;

    const int nch = (dd + 1) * 4;    // 32-wide K chunks
    #pragma unroll 2
    for (int c = w; c < nch; c += 16) {
        const int k = c * 32;
        bf16x8 a   = *(const bf16x8*)(Ab + k);
        bf16x8 b0v = *(const bf16x8*)(Bb[0] + k);
        bf16x8 b1w = *(const bf16x8*)(Bb[1] + k);
        acc[0] = __builtin_amdgcn_mfma_f32_16x16x32_bf16(a, b0v, acc[0], 0, 0, 0);
        acc[1] = __builtin_amdgcn_mfma_f32_16x16x32_bf16(a, b1w, acc[1], 0, 0, 0);
    }

    if (w < 4) {                     // grad matvec over diagonal 128-block
        const int k2 = dd * OB + w * 32;
        bf16x8 a = *(const bf16x8*)(e0 + (size_t)arow * NN + koff + k2);
        acc2[0] = __builtin_amdgcn_mfma_f32_16x16x32_bf16(a, *(const bf16x8*)(Bb[0] + k2), acc2[0], 0, 0, 0);
        acc2[1] = __builtin_amdgcn_mfma_f32_16x16x32_bf16(a, *(const bf16x8*)(Bb[1] + k2), acc2[1], 0, 0, 0);
    }

    #pragma unroll
    for (int nt = 0; nt < 2; ++nt)
        *(f32x4*)&ls1[w][nt][lane][0] = acc[nt];
    if (w < 4) {
        #pragma unroll
        for (int nt = 0; nt < 2; ++nt)
            *(f32x4*)&ls2[w][nt][lane][0] = acc2[nt];
    }
    __syncthreads();

    if (tid < 512) {
        const int o  = tid;                    // output index in tile
        const int rr = o >> 5;                 // 0..15 row
        const int cc = o & 31;                 // 0..31 col
        const int nt = cc >> 4;
        const int r  = rr & 3;
        const int ls = (rr >> 2) * 16 + (cc & 15);
        float S = 0.f, S2 = 0.f;
        #pragma unroll
        for (int ww = 0; ww < 16; ++ww) S += ls1[ww][nt][ls][r];
        #pragma unroll
        for (int ww = 0; ww < 4; ++ww) S2 += ls2[ww][nt][ls][r];
        const int j    = col0 + cc;
        const int brow = brow0 + rr;
        const float pre = S + b1v[j];
        float th, lga;
        act_tanh_lga(pre, th, lga);
        h1[(size_t)brow * NN + j] = f2bf(th);
        g1[(size_t)brow * NN + j] = __logf(S2) + mmax[brow * DBLK + dd] + lga;
    }
}

// ---- final-layer compute for one batch row, 1024 threads: wave w == dd ----
__device__ __forceinline__ float final_compute(const unsigned short* __restrict__ h1,
                                               const float* __restrict__ g1,
                                               const float* __restrict__ W2,
                                               int b, int tid,
                                               float* sh, float* gf, float* sx) {
    const int dd   = tid >> 6;
    const int lane = tid & 63;
    {
        const int k = tid * 2;
        ushort2 hv = *(const ushort2*)(h1 + (size_t)b * NN + k);
        sh[k]     = bf2f(hv.x);
        sh[k + 1] = bf2f(hv.y);
    }
    __syncthreads();

    const float* w2r = W2 + (size_t)dd * NN;
    const int kend = (dd + 1) * OB;
    float s = 0.f;
    for (int k = lane * 4; k < kend; k += 64 * 4) {
        float4 hv = *(const float4*)(sh + k);
        float4 wv = *(const float4*)(w2r + k);
        s += hv.x * wv.x + hv.y * wv.y + hv.z * wv.z + hv.w * wv.w;
    }
    #pragma unroll
    for (int off = 32; off > 0; off >>= 1) s += __shfl_xor(s, off);

    float v0 = g1[(size_t)b * NN + dd * OB + lane];
    float v1 = g1[(size_t)b * NN + dd * OB + 64 + lane];
    float m = fmaxf(v0, v1);
    #pragma unroll
    for (int off = 32; off > 0; off >>= 1) m = fmaxf(m, __shfl_xor(m, off));
    float e = __expf(v0 - m) * w2r[dd * OB + lane]
            + __expf(v1 - m) * w2r[dd * OB + 64 + lane];
    #pragma unroll
    for (int off = 32; off > 0; off >>= 1) e += __shfl_xor(e, off);
    if (lane == 0) {
        sx[dd] = s;
        gf[dd] = __logf(e) + m;
    }
    __syncthreads();
    float ld = 0.f;
    #pragma unroll
    for (int dd2 = 0; dd2 < DBLK; ++dd2) ld += gf[dd2];
    return ld;
}

struct Params {
    const float *inp;
    const float *W0a, *W1a, *W2a, *b0a, *b1a;   // flow 0
    const float *W0c, *W1c, *W2c, *b0c, *b1c;   // flow 1
    unsigned short *W1bf, *h0a, *e0a, *h0c, *e0c, *h1;
    float *mmax0, *mmax1, *g1, *ld0, *outF, *ldF;
};

// ================= cooperative mega-kernel (preferred path) =================
__global__ void __launch_bounds__(NT, 4) k_mega(Params P) {
    const int bid = blockIdx.x;
    const int tid = threadIdx.x;
    cg::grid_group grid = cg::this_grid();

    __shared__ float ls1[16][2][64][4];  // 32 KB
    __shared__ float ls2[4][2][64][4];   //  8 KB
    __shared__ float sh[NN];             //  8 KB
    __shared__ float gf[DBLK];
    __shared__ float sx[DBLK];

    // ---- P1: convert both W1 (triangular extent) + layer0 flow 0 ----
    conv_phase<3>(bid * NT + tid, NB * NT, P.W1a, P.W1c, P.W1bf);
    l0_wave(P.inp + (size_t)bid * DBLK, P.W0a, P.b0a, P.h0a, P.e0a, P.mmax0, bid, tid);
    grid.sync();

    // ---- P2: layer1 flow 0 (4 tiles/block, grid-strided) ----
    for (int idx = bid; idx < 1024; idx += NB)
        l1_tile(idx >> 6, (idx >> 2) & 15, idx & 3, tid,
                P.h0a, P.W1bf, P.b1a, P.e0a, P.mmax0, P.h1, P.g1, ls1, ls2);
    grid.sync();

    // ---- P3: final flow 0 + layer0 flow 1 (one batch row per block) ----
    {
        float ld = final_compute(P.h1, P.g1, P.W2a, bid, tid, sh, gf, sx);
        if (tid == 0) P.ld0[bid] = ld;
        l0_wave(sx, P.W0c, P.b0c, P.h0c, P.e0c, P.mmax1, bid, tid);
    }
    grid.sync();

    // ---- P4: layer1 flow 1 ----
    for (int idx = bid; idx < 1024; idx += NB)
        l1_tile(idx >> 6, (idx >> 2) & 15, idx & 3, tid,
                P.h0c, P.W1bf + (size_t)NN * NN, P.b1c, P.e0c, P.mmax1,
                P.h1, P.g1, ls1, ls2);
    grid.sync();

    // ---- P5: final flow 1 -> d_out ----
    {
        float ld = final_compute(P.h1, P.g1, P.W2c, bid, tid, sh, gf, sx);
        if (tid < DBLK) P.outF[bid * DBLK + tid] = sx[tid];
        if (tid == 0)   P.ldF[bid] = ld + P.ld0[bid];
    }
}

// ================= fallback path: 5 plain kernels (R7 structure) =================
__global__ void __launch_bounds__(NT, 4)
fb_prep(const float* W1a, const float* W1c, unsigned short* W1bf,
        const float* inp, const float* W0a, const float* b0a,
        unsigned short* h0a, unsigned short* e0a, float* mmax0) {
    const int gb = blockIdx.x;
    if (gb < 272)
        conv_phase<2>(gb * NT + threadIdx.x, 272 * NT, W1a, W1c, W1bf);
    else
        l0_wave(inp + (size_t)(gb - 272) * DBLK, W0a, b0a, h0a, e0a, mmax0,
                gb - 272, threadIdx.x);
}

__global__ void __launch_bounds__(NT, 4)
fb_l1(const unsigned short* h0, const unsigned short* W1b, const float* b1v,
      const unsigned short* e0, const float* mmax,
      unsigned short* h1, float* g1) {
    __shared__ float ls1[16][2][64][4];
    __shared__ float ls2[4][2][64][4];
    l1_tile(blockIdx.x, blockIdx.y, blockIdx.z, threadIdx.x,
            h0, W1b, b1v, e0, mmax, h1, g1, ls1, ls2);
}

__global__ void __launch_bounds__(NT, 4)
fb_fin0(const unsigned short* h1, const float* g1, const float* W2a,
        const float* W0c, const float* b0c,
        unsigned short* h0c, unsigned short* e0c, float* mmax1, float* ld0) {
    __shared__ float sh[NN];
    __shared__ float gf[DBLK];
    __shared__ float sx[DBLK];
    const int b = blockIdx.x;
    float ld = final_compute(h1, g1, W2a, b, threadIdx.x, sh, gf, sx);
    if (threadIdx.x == 0) ld0[b] = ld;
    l0_wave(sx, W0c, b0c, h0c, e0c, mmax1, b, threadIdx.x);
}

__global__ void __launch_bounds__(NT, 4)
fb_fin1(const unsigned short* h1, const float* g1, const float* W2c,
        const float* ld0, float* outF, float* ldF) {
    __shared__ float sh[NN];
    __shared__ float gf[DBLK];
    __shared__ float sx[DBLK];
    const int b = blockIdx.x;
    float ld = final_compute(h1, g1, W2c, b, threadIdx.x, sh, gf, sx);
    if (threadIdx.x < DBLK) outF[b * DBLK + threadIdx.x] = sx[threadIdx.x];
    if (threadIdx.x == 0)   ldF[b] = ld + ld0[b];
}

extern "C" void kernel_launch(void* const* d_in, const int* in_sizes, int n_in,
                              void* d_out, int out_size, void* d_ws, size_t ws_size,
                              hipStream_t stream) {
    char* w = (char*)d_ws;
    size_t off = 0;
    unsigned short* W1bf = (unsigned short*)(w + off); off += (size_t)2 * NN * NN * 2; // 16 MB
    unsigned short* h0a  = (unsigned short*)(w + off); off += (size_t)BATCH * NN * 2;
    unsigned short* e0a  = (unsigned short*)(w + off); off += (size_t)BATCH * NN * 2;
    unsigned short* h0c  = (unsigned short*)(w + off); off += (size_t)BATCH * NN * 2;
    unsigned short* e0c  = (unsigned short*)(w + off); off += (size_t)BATCH * NN * 2;
    unsigned short* h1   = (unsigned short*)(w + off); off += (size_t)BATCH * NN * 2;
    float* mmax0 = (float*)(w + off); off += (size_t)BATCH * DBLK * 4;
    float* mmax1 = (float*)(w + off); off += (size_t)BATCH * DBLK * 4;
    float* g1    = (float*)(w + off); off += (size_t)BATCH * NN * 4;
    float* ld0   = (float*)(w + off); off += (size_t)BATCH * 4;

    Params P;
    P.inp = (const float*)d_in[0];
    P.W0a = (const float*)d_in[1];  P.W1a = (const float*)d_in[2];
    P.W2a = (const float*)d_in[3];  P.b0a = (const float*)d_in[4];
    P.b1a = (const float*)d_in[5];
    P.W0c = (const float*)d_in[6];  P.W1c = (const float*)d_in[7];
    P.W2c = (const float*)d_in[8];  P.b0c = (const float*)d_in[9];
    P.b1c = (const float*)d_in[10];
    P.W1bf = W1bf; P.h0a = h0a; P.e0a = e0a; P.h0c = h0c; P.e0c = e0c; P.h1 = h1;
    P.mmax0 = mmax0; P.mmax1 = mmax1; P.g1 = g1; P.ld0 = ld0;
    P.outF = (float*)d_out;
    P.ldF  = (float*)d_out + BATCH * DBLK;

    void* args[] = { &P };
    hipError_t err = hipLaunchCooperativeKernel((const void*)k_mega, dim3(NB), dim3(NT),
                                                args, 0, stream);
    if (err != hipSuccess) {
        (void)hipGetLastError();   // clear sticky error; use plain-kernel fallback
        fb_prep<<<dim3(272 + BATCH), dim3(NT), 0, stream>>>(
            P.W1a, P.W1c, W1bf, P.inp, P.W0a, P.b0a, h0a, e0a, mmax0);
        fb_l1<<<dim3(DBLK, 16, 4), dim3(NT), 0, stream>>>(
            h0a, W1bf, P.b1a, e0a, mmax0, h1, g1);
        fb_fin0<<<dim3(BATCH), dim3(NT), 0, stream>>>(
            h1, g1, P.W2a, P.W0c, P.b0c, h0c, e0c, mmax1, ld0);
        fb_l1<<<dim3(DBLK, 16, 4), dim3(NT), 0, stream>>>(
            h0c, W1bf + (size_t)NN * NN, P.b1c, e0c, mmax1, h1, g1);
        fb_fin1<<<dim3(BATCH), dim3(NT), 0, stream>>>(
            h1, g1, P.W2c, ld0, P.outF, P.ldF);
    }
}

// Round 11
// 86.644 us; speedup vs baseline: 3.3101x; 2.2817x over previous
//
#include <hip/hip_runtime.h>
#include <stdint.h>

#define BATCH 256
#define DBLK  16          // d
#define OB    128         // hidden nodes per diagonal block (M)
#define NN    2048        // M*D

using bf16x8  = __attribute__((ext_vector_type(8))) __bf16;
using f32x4   = __attribute__((ext_vector_type(4))) float;
using ushort8 = __attribute__((ext_vector_type(8))) unsigned short;

__device__ __forceinline__ unsigned short f2bf(float f) {
    union { float f; uint32_t u; } v; v.f = f;
    uint32_t u = v.u;
    uint32_t r = (u + 0x7fffu + ((u >> 16) & 1u)) >> 16;   // RNE
    return (unsigned short)r;
}

__device__ __forceinline__ float bf2f(unsigned short h) {
    union { uint32_t u; float f; } v; v.u = ((uint32_t)h) << 16;
    return v.f;
}

// fused fast tanh + log|tanh'|: one __expf + one __logf.
__device__ __forceinline__ void act_tanh_lga(float x, float& th, float& lga) {
    float ax = fabsf(x);
    float e  = __expf(-2.f * ax);
    float p  = 1.f + e;
    float t  = 1.f - __fdividef(2.f * e, p);
    th  = (x < 0.f) ? -t : t;
    lga = 2.f * (0.69314718055994531f - ax - __logf(p));
}

__device__ __forceinline__ ushort8 pack_bf8(float4 a, float4 b) {
    ushort8 u;
    u[0] = f2bf(a.x); u[1] = f2bf(a.y); u[2] = f2bf(a.z); u[3] = f2bf(a.w);
    u[4] = f2bf(b.x); u[5] = f2bf(b.y); u[6] = f2bf(b.z); u[7] = f2bf(b.w);
    return u;
}

// ---- convert 4 row-pairs {p,2047-p} of one W1 (fp32->bf16, triangular extent),
//      512 threads, 1088 8-float chunks, 3 hoisted slots/thread (proven in R7)
__device__ __forceinline__ void conv4pairs(int cid, int tid,
                                           const float* __restrict__ Wsrc,
                                           unsigned short* __restrict__ Wdst) {
    float4 va[3][2];
    unsigned short* dp[3];
    bool act[3];
    #pragma unroll
    for (int i = 0; i < 3; ++i) {
        const int c = tid + i * 512;
        act[i] = (c < 1088);
        if (act[i]) {
            const int pi  = c / 272;
            const int rem = c - pi * 272;
            const int p   = cid * 4 + pi;
            const int kend0 = ((p >> 7) + 1) * OB;
            const int off = rem * 8;
            const int row = (off < kend0) ? p : (NN - 1 - p);
            const int k   = (off < kend0) ? off : (off - kend0);
            const float* sp = Wsrc + (size_t)row * NN + k;
            dp[i] = Wdst + (size_t)row * NN + k;
            va[i][0] = *(const float4*)(sp);
            va[i][1] = *(const float4*)(sp + 4);
        }
    }
    #pragma unroll
    for (int i = 0; i < 3; ++i)
        if (act[i]) *(ushort8*)dp[i] = pack_bf8(va[i][0], va[i][1]);
}

// ---- layer0, 512 threads: thread t -> outputs j = (t>>5)*128 + (t&31)*4 ..+3
__device__ __forceinline__ void l0_block512(const float* __restrict__ xs,
                                            const float* __restrict__ W0,
                                            const float* __restrict__ b0,
                                            unsigned short* __restrict__ h0,
                                            unsigned short* __restrict__ e0,
                                            float* __restrict__ mmax,
                                            int b, int t) {
    const int dd = t >> 5;
    const int j0 = dd * OB + (t & 31) * 4;
    float g[4];
    unsigned short hv[4];
    float lm = -1e30f;
    #pragma unroll
    for (int q = 0; q < 4; ++q) {
        const int j = j0 + q;
        const float* wrow = W0 + (size_t)j * DBLK;
        float s = b0[j];
        #pragma unroll
        for (int c = 0; c < DBLK; c += 4) {
            float4 wv = *(const float4*)(wrow + c);
            s += wv.x * xs[c] + wv.y * xs[c + 1] + wv.z * xs[c + 2] + wv.w * xs[c + 3];
        }
        float th, lga;
        act_tanh_lga(s, th, lga);
        hv[q] = f2bf(th);
        g[q]  = __logf(wrow[dd]) + lga;
        lm = fmaxf(lm, g[q]);
    }
    #pragma unroll
    for (int off = 1; off < 32; off <<= 1) lm = fmaxf(lm, __shfl_xor(lm, off));
    ushort4 hh, ee;
    #pragma unroll
    for (int q = 0; q < 4; ++q) {
        ((unsigned short*)&hh)[q] = hv[q];
        ((unsigned short*)&ee)[q] = f2bf(__expf(g[q] - lm));
    }
    *(ushort4*)(h0 + (size_t)b * NN + j0) = hh;
    *(ushort4*)(e0 + (size_t)b * NN + j0) = ee;
    if ((t & 31) == 0) mmax[b * DBLK + dd] = lm;
}

// ---- P1: blocks [0,256): convert flow0 W1 (4 row-pairs each, deep pipeline);
//          blocks [256,512): layer0 of flow 0
__global__ void __launch_bounds__(512)
k_prep(const float* __restrict__ W1a,
       unsigned short* __restrict__ W1bf,
       const float* __restrict__ inp,
       const float* __restrict__ W00,
       const float* __restrict__ b00,
       unsigned short* __restrict__ h0,
       unsigned short* __restrict__ e0,
       float* __restrict__ mmax) {
    const int gb = blockIdx.x;
    const int t  = threadIdx.x;
    if (gb < 256) {
        conv4pairs(gb, t, W1a, W1bf);
    } else {
        const int b = gb - 256;
        l0_block512(inp + (size_t)b * DBLK, W00, b00, h0, e0, mmax, b, t);
    }
}

// ---- layer1. grid (dd=16, bt=16, z), 512 thr (8 waves).
// z<4: tile = 16 batch rows x 32 cols, waves take interleaved 32-wide K-chunks.
// CONV && z==4: convert flow1 W1 (4 row-pairs per block).
template<bool CONV>
__global__ void __launch_bounds__(512, 4)
k_l1(const unsigned short* __restrict__ h0,
     const unsigned short* __restrict__ W1b,
     const float* __restrict__ b1v,
     const unsigned short* __restrict__ e0,
     const float* __restrict__ mmax,
     unsigned short* __restrict__ h1,
     float* __restrict__ g1,
     const float* __restrict__ W1next,
     unsigned short* __restrict__ W1bfn) {
    const int tid = threadIdx.x;

    if (CONV && blockIdx.z == 4) {
        const int cid = (int)blockIdx.x * 16 + (int)blockIdx.y;   // 0..255
        conv4pairs(cid, tid, W1next, W1bfn);
        return;
    }

    const int dd    = blockIdx.x;
    const int bt    = blockIdx.y;
    const int ct    = blockIdx.z;
    const int w     = tid >> 6;      // 0..7
    const int lane  = tid & 63;
    const int brow0 = bt * 16;
    const int arow  = brow0 + (lane & 15);
    const int koff  = (lane >> 4) * 8;
    const int ncol  = lane & 15;
    const int col0  = dd * OB + ct * 32;

    f32x4 acc[2], acc2[2];
    #pragma unroll
    for (int nt = 0; nt < 2; ++nt) {
        acc[nt]  = (f32x4){0.f, 0.f, 0.f, 0.f};
        acc2[nt] = (f32x4){0.f, 0.f, 0.f, 0.f};
    }

    const unsigned short* Ab = h0 + (size_t)arow * NN + koff;
    const unsigned short* Bb[2];
    #pragma unroll
    for (int nt = 0; nt < 2; ++nt)
        Bb[nt] = W1b + (size_t)(col0 + nt * 16 + ncol) * NN + koff;

    // grad-matvec loads hoisted: issue BEFORE the main MFMA chain so their
    // latency overlaps the GEMM loop (waves 0..3 only use them).
    bf16x8 ga  = {};
    bf16x8 gb0 = {};
    bf16x8 gb1 = {};
    if (w < 4) {
        const int k2 = dd * OB + w * 32;
        ga  = *(const bf16x8*)(e0 + (size_t)arow * NN + koff + k2);
        gb0 = *(const bf16x8*)(Bb[0] + k2);
        gb1 = *(const bf16x8*)(Bb[1] + k2);
    }

    // GEMM: wave w takes chunks c = w, w+8, ... of the (dd+1)*4 chunks
    const int nch = (dd + 1) * 4;
    #pragma unroll 4
    for (int c = w; c < nch; c += 8) {
        const int k = c * 32;
        bf16x8 a   = *(const bf16x8*)(Ab + k);
        bf16x8 b0v = *(const bf16x8*)(Bb[0] + k);
        bf16x8 b1w = *(const bf16x8*)(Bb[1] + k);
        acc[0] = __builtin_amdgcn_mfma_f32_16x16x32_bf16(a, b0v, acc[0], 0, 0, 0);
        acc[1] = __builtin_amdgcn_mfma_f32_16x16x32_bf16(a, b1w, acc[1], 0, 0, 0);
    }

    if (w < 4) {
        acc2[0] = __builtin_amdgcn_mfma_f32_16x16x32_bf16(ga, gb0, acc2[0], 0, 0, 0);
        acc2[1] = __builtin_amdgcn_mfma_f32_16x16x32_bf16(ga, gb1, acc2[1], 0, 0, 0);
    }

    __shared__ float ls1[8][2][64][4];
    __shared__ float ls2[4][2][64][4];
    #pragma unroll
    for (int nt = 0; nt < 2; ++nt)
        *(f32x4*)&ls1[w][nt][lane][0] = acc[nt];
    if (w < 4) {
        #pragma unroll
        for (int nt = 0; nt < 2; ++nt)
            *(f32x4*)&ls2[w][nt][lane][0] = acc2[nt];
    }
    __syncthreads();

    {
        const int o  = tid;                    // 0..511 output index in tile
        const int rr = o >> 5;                 // 0..15 row in tile
        const int cc = o & 31;                 // 0..31 col in tile
        const int nt = cc >> 4;
        const int r  = rr & 3;
        const int ls = (rr >> 2) * 16 + (cc & 15);
        float S = 0.f, S2 = 0.f;
        #pragma unroll
        for (int ww = 0; ww < 8; ++ww) S += ls1[ww][nt][ls][r];
        #pragma unroll
        for (int ww = 0; ww < 4; ++ww) S2 += ls2[ww][nt][ls][r];
        const int j    = col0 + cc;
        const int brow = brow0 + rr;
        const float pre = S + b1v[j];
        float th, lga;
        act_tanh_lga(pre, th, lga);
        h1[(size_t)brow * NN + j] = f2bf(th);
        g1[(size_t)brow * NN + j] = __logf(S2) + mmax[brow * DBLK + dd] + lga;
    }
}

// ---- final-layer compute for one batch row, 512 threads: wave w -> dd = w, w+8.
__device__ __forceinline__ float final_compute(const unsigned short* __restrict__ h1,
                                               const float* __restrict__ g1,
                                               const float* __restrict__ W2,
                                               int b, int t,
                                               float* sh, float* gf, float* sx) {
    const int wave = t >> 6;
    const int lane = t & 63;
    {
        const int k = t * 4;
        ushort4 hv = *(const ushort4*)(h1 + (size_t)b * NN + k);
        float4 f0;
        f0.x = bf2f(hv.x); f0.y = bf2f(hv.y); f0.z = bf2f(hv.z); f0.w = bf2f(hv.w);
        *(float4*)(sh + k) = f0;
    }
    __syncthreads();

    #pragma unroll
    for (int q = 0; q < 2; ++q) {
        const int dd = wave + q * 8;           // balanced: (w+1)+(w+9) const
        const float* w2r = W2 + (size_t)dd * NN;
        const int kend = (dd + 1) * OB;
        float s = 0.f;
        for (int k = lane * 4; k < kend; k += 64 * 4) {
            float4 hv = *(const float4*)(sh + k);
            float4 wv = *(const float4*)(w2r + k);
            s += hv.x * wv.x + hv.y * wv.y + hv.z * wv.z + hv.w * wv.w;
        }
        #pragma unroll
        for (int off = 32; off > 0; off >>= 1) s += __shfl_xor(s, off);
        float v0 = g1[(size_t)b * NN + dd * OB + lane];
        float v1 = g1[(size_t)b * NN + dd * OB + 64 + lane];
        float m = fmaxf(v0, v1);
        #pragma unroll
        for (int off = 32; off > 0; off >>= 1) m = fmaxf(m, __shfl_xor(m, off));
        float e = __expf(v0 - m) * w2r[dd * OB + lane]
                + __expf(v1 - m) * w2r[dd * OB + 64 + lane];
        #pragma unroll
        for (int off = 32; off > 0; off >>= 1) e += __shfl_xor(e, off);
        if (lane == 0) {
            sx[dd] = s;
            gf[dd] = __logf(e) + m;
        }
    }
    __syncthreads();
    float ld = 0.f;
    #pragma unroll
    for (int dd = 0; dd < DBLK; ++dd) ld += gf[dd];
    return ld;
}

// ---- P3: final of flow 0 + layer0 of flow 1 (block b = batch row b)
__global__ void __launch_bounds__(512)
k_fin0(const unsigned short* __restrict__ h1,
       const float* __restrict__ g1,
       const float* __restrict__ W2,   // flow 0
       const float* __restrict__ W0n,  // flow 1
       const float* __restrict__ b0n,  // flow 1
       unsigned short* __restrict__ h0,
       unsigned short* __restrict__ e0,
       float* __restrict__ mmax,
       float* __restrict__ ld0) {
    __shared__ float sh[NN];
    __shared__ float gf[DBLK];
    __shared__ float sx[DBLK];
    const int b = blockIdx.x;
    const int t = threadIdx.x;
    float ld = final_compute(h1, g1, W2, b, t, sh, gf, sx);
    if (t == 0) ld0[b] = ld;
    l0_block512(sx, W0n, b0n, h0, e0, mmax, b, t);
}

// ---- P5: final of flow 1 -> d_out
__global__ void __launch_bounds__(512)
k_fin1(const unsigned short* __restrict__ h1,
       const float* __restrict__ g1,
       const float* __restrict__ W2,   // flow 1
       const float* __restrict__ ld0,
       float* __restrict__ out_final,
       float* __restrict__ ld_final) {
    __shared__ float sh[NN];
    __shared__ float gf[DBLK];
    __shared__ float sx[DBLK];
    const int b = blockIdx.x;
    const int t = threadIdx.x;
    float ld = final_compute(h1, g1, W2, b, t, sh, gf, sx);
    if (t < DBLK) out_final[b * DBLK + t] = sx[t];
    if (t == 0) ld_final[b] = ld + ld0[b];
}

extern "C" void kernel_launch(void* const* d_in, const int* in_sizes, int n_in,
                              void* d_out, int out_size, void* d_ws, size_t ws_size,
                              hipStream_t stream) {
    const float* inp   = (const float*)d_in[0];
    const float* W0[2] = {(const float*)d_in[1], (const float*)d_in[6]};
    const float* W1[2] = {(const float*)d_in[2], (const float*)d_in[7]};
    const float* W2[2] = {(const float*)d_in[3], (const float*)d_in[8]};
    const float* b0[2] = {(const float*)d_in[4], (const float*)d_in[9]};
    const float* b1[2] = {(const float*)d_in[5], (const float*)d_in[10]};

    char* w = (char*)d_ws;
    size_t off = 0;
    unsigned short* W1bf = (unsigned short*)(w + off); off += (size_t)2 * NN * NN * 2; // 16 MB
    unsigned short* h0b  = (unsigned short*)(w + off); off += (size_t)BATCH * NN * 2;
    unsigned short* e0b  = (unsigned short*)(w + off); off += (size_t)BATCH * NN * 2;
    float* mmax = (float*)(w + off); off += (size_t)BATCH * DBLK * 4;
    unsigned short* h1 = (unsigned short*)(w + off); off += (size_t)BATCH * NN * 2;
    float* g1   = (float*)(w + off); off += (size_t)BATCH * NN * 4;
    float* ld0  = (float*)(w + off); off += (size_t)BATCH * 4;

    float* out_final = (float*)d_out;                 // (256,16)
    float* ld_final  = (float*)d_out + BATCH * DBLK;  // (256,)

    // P1: convert flow0 W1 (deep-pipelined) + layer0 flow 0
    k_prep<<<dim3(512), dim3(512), 0, stream>>>(
        W1[0], W1bf, inp, W0[0], b0[0], h0b, e0b, mmax);

    // P2: layer1 flow 0  ∥  convert flow1 W1 (z==4 blocks)
    k_l1<true><<<dim3(DBLK, 16, 5), dim3(512), 0, stream>>>(
        h0b, W1bf, b1[0], e0b, mmax, h1, g1,
        W1[1], W1bf + (size_t)NN * NN);

    // P3: final flow 0 + layer0 flow 1
    k_fin0<<<dim3(BATCH), dim3(512), 0, stream>>>(
        h1, g1, W2[0], W0[1], b0[1], h0b, e0b, mmax, ld0);

    // P4: layer1 flow 1
    k_l1<false><<<dim3(DBLK, 16, 4), dim3(512), 0, stream>>>(
        h0b, W1bf + (size_t)NN * NN, b1[1], e0b, mmax, h1, g1,
        nullptr, nullptr);

    // P5: final flow 1
    k_fin1<<<dim3(BATCH), dim3(512), 0, stream>>>(
        h1, g1, W2[1], ld0, out_final, ld_final);
}

// Round 12
// 76.749 us; speedup vs baseline: 3.7368x; 1.1289x over previous
//
#include <hip/hip_runtime.h>
#include <stdint.h>

#define BATCH 256
#define DBLK  16          // d
#define OB    128         // hidden nodes per diagonal block (M)
#define NN    2048        // M*D

using bf16x8  = __attribute__((ext_vector_type(8))) __bf16;
using f32x4   = __attribute__((ext_vector_type(4))) float;
using ushort8 = __attribute__((ext_vector_type(8))) unsigned short;

__device__ __forceinline__ unsigned short f2bf(float f) {
    union { float f; uint32_t u; } v; v.f = f;
    uint32_t u = v.u;
    uint32_t r = (u + 0x7fffu + ((u >> 16) & 1u)) >> 16;   // RNE
    return (unsigned short)r;
}

__device__ __forceinline__ float bf2f(unsigned short h) {
    union { uint32_t u; float f; } v; v.u = ((uint32_t)h) << 16;
    return v.f;
}

// fused fast tanh + log|tanh'|: one __expf + one __logf.
__device__ __forceinline__ void act_tanh_lga(float x, float& th, float& lga) {
    float ax = fabsf(x);
    float e  = __expf(-2.f * ax);
    float p  = 1.f + e;
    float t  = 1.f - __fdividef(2.f * e, p);
    th  = (x < 0.f) ? -t : t;
    lga = 2.f * (0.69314718055994531f - ax - __logf(p));
}

__device__ __forceinline__ ushort8 pack_bf8(float4 a, float4 b) {
    ushort8 u;
    u[0] = f2bf(a.x); u[1] = f2bf(a.y); u[2] = f2bf(a.z); u[3] = f2bf(a.w);
    u[4] = f2bf(b.x); u[5] = f2bf(b.y); u[6] = f2bf(b.z); u[7] = f2bf(b.w);
    return u;
}

// ---- convert 8 row-pairs {p,2047-p} of one W1 (fp32->bf16, triangular extent).
// 512 threads, 2176 8-float chunks, 5 hoisted load slots per thread.
__device__ __forceinline__ void conv8pairs(int cid, int tid,
                                           const float* __restrict__ Wsrc,
                                           unsigned short* __restrict__ Wdst) {
    float4 va[5][2];
    unsigned short* dp[5];
    bool act[5];
    #pragma unroll
    for (int i = 0; i < 5; ++i) {
        const int c = tid + i * 512;
        act[i] = (c < 2176);
        if (act[i]) {
            const int pi  = c / 272;
            const int rem = c - pi * 272;
            const int p   = cid * 8 + pi;
            const int kend0 = ((p >> 7) + 1) * OB;
            const int off = rem * 8;
            const int row = (off < kend0) ? p : (NN - 1 - p);
            const int k   = (off < kend0) ? off : (off - kend0);
            const float* sp = Wsrc + (size_t)row * NN + k;
            dp[i] = Wdst + (size_t)row * NN + k;
            va[i][0] = *(const float4*)(sp);
            va[i][1] = *(const float4*)(sp + 4);
        }
    }
    #pragma unroll
    for (int i = 0; i < 5; ++i)
        if (act[i]) *(ushort8*)dp[i] = pack_bf8(va[i][0], va[i][1]);
}

// ---- layer0, 512 threads: thread t -> outputs j = (t>>5)*128 + (t&31)*4 ..+3
__device__ __forceinline__ void l0_block512(const float* __restrict__ xs,
                                            const float* __restrict__ W0,
                                            const float* __restrict__ b0,
                                            unsigned short* __restrict__ h0,
                                            unsigned short* __restrict__ e0,
                                            float* __restrict__ mmax,
                                            int b, int t) {
    const int dd = t >> 5;
    const int j0 = dd * OB + (t & 31) * 4;
    float g[4];
    unsigned short hv[4];
    float lm = -1e30f;
    #pragma unroll
    for (int q = 0; q < 4; ++q) {
        const int j = j0 + q;
        const float* wrow = W0 + (size_t)j * DBLK;
        float s = b0[j];
        #pragma unroll
        for (int c = 0; c < DBLK; c += 4) {
            float4 wv = *(const float4*)(wrow + c);
            s += wv.x * xs[c] + wv.y * xs[c + 1] + wv.z * xs[c + 2] + wv.w * xs[c + 3];
        }
        float th, lga;
        act_tanh_lga(s, th, lga);
        hv[q] = f2bf(th);
        g[q]  = __logf(wrow[dd]) + lga;
        lm = fmaxf(lm, g[q]);
    }
    #pragma unroll
    for (int off = 1; off < 32; off <<= 1) lm = fmaxf(lm, __shfl_xor(lm, off));
    ushort4 hh, ee;
    #pragma unroll
    for (int q = 0; q < 4; ++q) {
        ((unsigned short*)&hh)[q] = hv[q];
        ((unsigned short*)&ee)[q] = f2bf(__expf(g[q] - lm));
    }
    *(ushort4*)(h0 + (size_t)b * NN + j0) = hh;
    *(ushort4*)(e0 + (size_t)b * NN + j0) = ee;
    if ((t & 31) == 0) mmax[b * DBLK + dd] = lm;
}

// ---- P1: blocks [0,128): convert flow0 W1 (8 row-pairs each, deep pipeline);
//          blocks [128,384): layer0 of flow 0
__global__ void __launch_bounds__(512)
k_prep(const float* __restrict__ W1a,
       unsigned short* __restrict__ W1bf,
       const float* __restrict__ inp,
       const float* __restrict__ W00,
       const float* __restrict__ b00,
       unsigned short* __restrict__ h0,
       unsigned short* __restrict__ e0,
       float* __restrict__ mmax) {
    const int gb = blockIdx.x;
    const int t  = threadIdx.x;
    if (gb < 128) {
        conv8pairs(gb, t, W1a, W1bf);
    } else {
        const int b = gb - 128;
        l0_block512(inp + (size_t)b * DBLK, W00, b00, h0, e0, mmax, b, t);
    }
}

// ---- layer1. 512 thr (8 waves). Output tile = 32 rows x 32 cols (2 bt halves
// share B loads: 4 loads -> 4 MFMA per chunk). Waves split K 8 ways interleaved.
// CONV grid (20,8,4): x<4 = convert flow1 W1 (conv FIRST in dispatch order),
//                     x>=4 = GEMM with dd = 19-x (heavy dd first).
// !CONV grid (16,8,4): dd = 15-x.
template<bool CONV>
__global__ void __launch_bounds__(512, 2)
k_l1(const unsigned short* __restrict__ h0,
     const unsigned short* __restrict__ W1b,
     const float* __restrict__ b1v,
     const unsigned short* __restrict__ e0,
     const float* __restrict__ mmax,
     unsigned short* __restrict__ h1,
     float* __restrict__ g1,
     const float* __restrict__ W1next,
     unsigned short* __restrict__ W1bfn) {
    const int tid = threadIdx.x;

    int dd;
    if (CONV) {
        if (blockIdx.x < 4) {
            const int cid = (int)blockIdx.x * 32 + (int)blockIdx.y * 4 + (int)blockIdx.z;
            conv8pairs(cid, tid, W1next, W1bfn);
            return;
        }
        dd = 19 - (int)blockIdx.x;
    } else {
        dd = 15 - (int)blockIdx.x;
    }
    const int btp   = blockIdx.y;    // 0..7  (pair of 16-row tiles)
    const int ct    = blockIdx.z;    // 0..3
    const int w     = tid >> 6;      // 0..7
    const int lane  = tid & 63;
    const int brow0 = btp * 32;
    const int arow0 = brow0 + (lane & 15);
    const int arow1 = arow0 + 16;
    const int koff  = (lane >> 4) * 8;
    const int ncol  = lane & 15;
    const int col0  = dd * OB + ct * 32;

    f32x4 acc[2][2], acc2[2][2];
    #pragma unroll
    for (int hh = 0; hh < 2; ++hh)
        #pragma unroll
        for (int nt = 0; nt < 2; ++nt) {
            acc[hh][nt]  = (f32x4){0.f, 0.f, 0.f, 0.f};
            acc2[hh][nt] = (f32x4){0.f, 0.f, 0.f, 0.f};
        }

    const unsigned short* Ab0 = h0 + (size_t)arow0 * NN + koff;
    const unsigned short* Ab1 = h0 + (size_t)arow1 * NN + koff;
    const unsigned short* Bb[2];
    #pragma unroll
    for (int nt = 0; nt < 2; ++nt)
        Bb[nt] = W1b + (size_t)(col0 + nt * 16 + ncol) * NN + koff;

    // grad-matvec loads hoisted before the GEMM chain (waves 0..3 use them)
    bf16x8 ga0 = {}, ga1 = {}, gb0 = {}, gb1 = {};
    if (w < 4) {
        const int k2 = dd * OB + w * 32;
        ga0 = *(const bf16x8*)(e0 + (size_t)arow0 * NN + koff + k2);
        ga1 = *(const bf16x8*)(e0 + (size_t)arow1 * NN + koff + k2);
        gb0 = *(const bf16x8*)(Bb[0] + k2);
        gb1 = *(const bf16x8*)(Bb[1] + k2);
    }

    // GEMM: wave w takes chunks c = w, w+8, ... of the (dd+1)*4 chunks
    const int nch = (dd + 1) * 4;
    #pragma unroll 2
    for (int c = w; c < nch; c += 8) {
        const int k = c * 32;
        bf16x8 a0  = *(const bf16x8*)(Ab0 + k);
        bf16x8 a1  = *(const bf16x8*)(Ab1 + k);
        bf16x8 b0v = *(const bf16x8*)(Bb[0] + k);
        bf16x8 b1w = *(const bf16x8*)(Bb[1] + k);
        acc[0][0] = __builtin_amdgcn_mfma_f32_16x16x32_bf16(a0, b0v, acc[0][0], 0, 0, 0);
        acc[0][1] = __builtin_amdgcn_mfma_f32_16x16x32_bf16(a0, b1w, acc[0][1], 0, 0, 0);
        acc[1][0] = __builtin_amdgcn_mfma_f32_16x16x32_bf16(a1, b0v, acc[1][0], 0, 0, 0);
        acc[1][1] = __builtin_amdgcn_mfma_f32_16x16x32_bf16(a1, b1w, acc[1][1], 0, 0, 0);
    }

    if (w < 4) {
        acc2[0][0] = __builtin_amdgcn_mfma_f32_16x16x32_bf16(ga0, gb0, acc2[0][0], 0, 0, 0);
        acc2[0][1] = __builtin_amdgcn_mfma_f32_16x16x32_bf16(ga0, gb1, acc2[0][1], 0, 0, 0);
        acc2[1][0] = __builtin_amdgcn_mfma_f32_16x16x32_bf16(ga1, gb0, acc2[1][0], 0, 0, 0);
        acc2[1][1] = __builtin_amdgcn_mfma_f32_16x16x32_bf16(ga1, gb1, acc2[1][1], 0, 0, 0);
    }

    __shared__ float ls1[8][2][2][64][4];   // [w][half][nt][lane][r]  32 KB
    __shared__ float ls2[4][2][2][64][4];   //                         16 KB
    #pragma unroll
    for (int hh = 0; hh < 2; ++hh)
        #pragma unroll
        for (int nt = 0; nt < 2; ++nt)
            *(f32x4*)&ls1[w][hh][nt][lane][0] = acc[hh][nt];
    if (w < 4) {
        #pragma unroll
        for (int hh = 0; hh < 2; ++hh)
            #pragma unroll
            for (int nt = 0; nt < 2; ++nt)
                *(f32x4*)&ls2[w][hh][nt][lane][0] = acc2[hh][nt];
    }
    __syncthreads();

    #pragma unroll
    for (int half = 0; half < 2; ++half) {
        const int o   = tid;                   // 512 outputs per half
        const int rr2 = o >> 5;                // 0..15 row within half
        const int cc  = o & 31;                // 0..31 col in tile
        const int nt  = cc >> 4;
        const int r   = rr2 & 3;
        const int ls  = (rr2 >> 2) * 16 + (cc & 15);
        float S = 0.f, S2 = 0.f;
        #pragma unroll
        for (int ww = 0; ww < 8; ++ww) S += ls1[ww][half][nt][ls][r];
        #pragma unroll
        for (int ww = 0; ww < 4; ++ww) S2 += ls2[ww][half][nt][ls][r];
        const int j    = col0 + cc;
        const int brow = brow0 + half * 16 + rr2;
        const float pre = S + b1v[j];
        float th, lga;
        act_tanh_lga(pre, th, lga);
        h1[(size_t)brow * NN + j] = f2bf(th);
        g1[(size_t)brow * NN + j] = __logf(S2) + mmax[brow * DBLK + dd] + lga;
    }
}

// ---- final-layer compute for one batch row, 512 threads: wave w -> dd = w, w+8.
__device__ __forceinline__ float final_compute(const unsigned short* __restrict__ h1,
                                               const float* __restrict__ g1,
                                               const float* __restrict__ W2,
                                               int b, int t,
                                               float* sh, float* gf, float* sx) {
    const int wave = t >> 6;
    const int lane = t & 63;
    {
        const int k = t * 4;
        ushort4 hv = *(const ushort4*)(h1 + (size_t)b * NN + k);
        float4 f0;
        f0.x = bf2f(hv.x); f0.y = bf2f(hv.y); f0.z = bf2f(hv.z); f0.w = bf2f(hv.w);
        *(float4*)(sh + k) = f0;
    }
    __syncthreads();

    #pragma unroll
    for (int q = 0; q < 2; ++q) {
        const int dd = wave + q * 8;           // balanced: (w+1)+(w+9) const
        const float* w2r = W2 + (size_t)dd * NN;
        const int kend = (dd + 1) * OB;
        float s = 0.f;
        for (int k = lane * 4; k < kend; k += 64 * 4) {
            float4 hv = *(const float4*)(sh + k);
            float4 wv = *(const float4*)(w2r + k);
            s += hv.x * wv.x + hv.y * wv.y + hv.z * wv.z + hv.w * wv.w;
        }
        #pragma unroll
        for (int off = 32; off > 0; off >>= 1) s += __shfl_xor(s, off);
        float v0 = g1[(size_t)b * NN + dd * OB + lane];
        float v1 = g1[(size_t)b * NN + dd * OB + 64 + lane];
        float m = fmaxf(v0, v1);
        #pragma unroll
        for (int off = 32; off > 0; off >>= 1) m = fmaxf(m, __shfl_xor(m, off));
        float e = __expf(v0 - m) * w2r[dd * OB + lane]
                + __expf(v1 - m) * w2r[dd * OB + 64 + lane];
        #pragma unroll
        for (int off = 32; off > 0; off >>= 1) e += __shfl_xor(e, off);
        if (lane == 0) {
            sx[dd] = s;
            gf[dd] = __logf(e) + m;
        }
    }
    __syncthreads();
    float ld = 0.f;
    #pragma unroll
    for (int dd = 0; dd < DBLK; ++dd) ld += gf[dd];
    return ld;
}

// ---- P3: final of flow 0 + layer0 of flow 1 (block b = batch row b)
__global__ void __launch_bounds__(512)
k_fin0(const unsigned short* __restrict__ h1,
       const float* __restrict__ g1,
       const float* __restrict__ W2,   // flow 0
       const float* __restrict__ W0n,  // flow 1
       const float* __restrict__ b0n,  // flow 1
       unsigned short* __restrict__ h0,
       unsigned short* __restrict__ e0,
       float* __restrict__ mmax,
       float* __restrict__ ld0) {
    __shared__ float sh[NN];
    __shared__ float gf[DBLK];
    __shared__ float sx[DBLK];
    const int b = blockIdx.x;
    const int t = threadIdx.x;
    float ld = final_compute(h1, g1, W2, b, t, sh, gf, sx);
    if (t == 0) ld0[b] = ld;
    l0_block512(sx, W0n, b0n, h0, e0, mmax, b, t);
}

// ---- P5: final of flow 1 -> d_out
__global__ void __launch_bounds__(512)
k_fin1(const unsigned short* __restrict__ h1,
       const float* __restrict__ g1,
       const float* __restrict__ W2,   // flow 1
       const float* __restrict__ ld0,
       float* __restrict__ out_final,
       float* __restrict__ ld_final) {
    __shared__ float sh[NN];
    __shared__ float gf[DBLK];
    __shared__ float sx[DBLK];
    const int b = blockIdx.x;
    const int t = threadIdx.x;
    float ld = final_compute(h1, g1, W2, b, t, sh, gf, sx);
    if (t < DBLK) out_final[b * DBLK + t] = sx[t];
    if (t == 0) ld_final[b] = ld + ld0[b];
}

extern "C" void kernel_launch(void* const* d_in, const int* in_sizes, int n_in,
                              void* d_out, int out_size, void* d_ws, size_t ws_size,
                              hipStream_t stream) {
    const float* inp   = (const float*)d_in[0];
    const float* W0[2] = {(const float*)d_in[1], (const float*)d_in[6]};
    const float* W1[2] = {(const float*)d_in[2], (const float*)d_in[7]};
    const float* W2[2] = {(const float*)d_in[3], (const float*)d_in[8]};
    const float* b0[2] = {(const float*)d_in[4], (const float*)d_in[9]};
    const float* b1[2] = {(const float*)d_in[5], (const float*)d_in[10]};

    char* w = (char*)d_ws;
    size_t off = 0;
    unsigned short* W1bf = (unsigned short*)(w + off); off += (size_t)2 * NN * NN * 2; // 16 MB
    unsigned short* h0b  = (unsigned short*)(w + off); off += (size_t)BATCH * NN * 2;
    unsigned short* e0b  = (unsigned short*)(w + off); off += (size_t)BATCH * NN * 2;
    float* mmax = (float*)(w + off); off += (size_t)BATCH * DBLK * 4;
    unsigned short* h1 = (unsigned short*)(w + off); off += (size_t)BATCH * NN * 2;
    float* g1   = (float*)(w + off); off += (size_t)BATCH * NN * 4;
    float* ld0  = (float*)(w + off); off += (size_t)BATCH * 4;

    float* out_final = (float*)d_out;                 // (256,16)
    float* ld_final  = (float*)d_out + BATCH * DBLK;  // (256,)

    // P1: convert flow0 W1 (128 deep-pipelined blocks) + layer0 flow 0
    k_prep<<<dim3(384), dim3(512), 0, stream>>>(
        W1[0], W1bf, inp, W0[0], b0[0], h0b, e0b, mmax);

    // P2: layer1 flow 0 (2-bt tiles, dd descending) ∥ convert flow1 W1 (x<4, first)
    k_l1<true><<<dim3(20, 8, 4), dim3(512), 0, stream>>>(
        h0b, W1bf, b1[0], e0b, mmax, h1, g1,
        W1[1], W1bf + (size_t)NN * NN);

    // P3: final flow 0 + layer0 flow 1
    k_fin0<<<dim3(BATCH), dim3(512), 0, stream>>>(
        h1, g1, W2[0], W0[1], b0[1], h0b, e0b, mmax, ld0);

    // P4: layer1 flow 1 (2-bt tiles, dd descending)
    k_l1<false><<<dim3(16, 8, 4), dim3(512), 0, stream>>>(
        h0b, W1bf + (size_t)NN * NN, b1[1], e0b, mmax, h1, g1,
        nullptr, nullptr);

    // P5: final flow 1
    k_fin1<<<dim3(BATCH), dim3(512), 0, stream>>>(
        h1, g1, W2[1], ld0, out_final, ld_final);
}